// Round 3
// baseline (259.052 us; speedup 1.0000x reference)
//
#include <hip/hip_runtime.h>

#define NPTS 131072
#define NE 8
#define DIN 90
#define NH 256

typedef __attribute__((ext_vector_type(8))) short bf16x8;
typedef __attribute__((ext_vector_type(4))) short bf16x4;
typedef __attribute__((ext_vector_type(4))) float f32x4;
typedef __attribute__((ext_vector_type(2))) float f32x2;
typedef __attribute__((ext_vector_type(4))) unsigned int u32x4;
typedef __attribute__((ext_vector_type(2))) unsigned int u32x2;
typedef __attribute__((ext_vector_type(4), aligned(4))) float f32x4a;
typedef __attribute__((ext_vector_type(2), aligned(4))) float f32x2a;

// exact RNE scalar (prep only)
__device__ __forceinline__ unsigned short f2bf(float f) {
  unsigned int u = __float_as_uint(f);
  u += 0x7fffu + ((u >> 16) & 1u);
  return (unsigned short)(u >> 16);
}

#if defined(__has_builtin) && __has_builtin(__builtin_amdgcn_cvt_pk_bf16_f32)
typedef __attribute__((ext_vector_type(2))) __bf16 bf16x2;
__device__ __forceinline__ unsigned int pkbf(float f0, float f1) {
  bf16x2 r = __builtin_amdgcn_cvt_pk_bf16_f32(f0, f1);
  return __builtin_bit_cast(unsigned int, r);
}
#else
__device__ __forceinline__ unsigned int pkbf(float f0, float f1) {
  unsigned int u0 = __float_as_uint(f0) + 0x7fffu;
  unsigned int u1 = __float_as_uint(f1) + 0x7fffu;
  return __builtin_amdgcn_perm(u1, u0, 0x07060302u);
}
#endif

__device__ __forceinline__ bf16x8 cvt8(f32x4 a, f32x4 b) {
  u32x4 r;
  r[0] = pkbf(a[0], a[1]);
  r[1] = pkbf(a[2], a[3]);
  r[2] = pkbf(b[0], b[1]);
  r[3] = pkbf(b[2], b[3]);
  return __builtin_bit_cast(bf16x8, r);
}

// 16x16x16 bf16 MFMA: A-frag = 4 bf16/lane, row=l15, k=l4*4+j  -- exactly the
// C/D layout of a 16x16 MFMA output after packing (hidden=l4*4+r, point=l15).
__device__ __forceinline__ f32x4 mfma16(bf16x4 a, bf16x4 b, f32x4 c) {
#if defined(__has_builtin) && __has_builtin(__builtin_amdgcn_mfma_f32_16x16x16bf16_1k)
  return __builtin_amdgcn_mfma_f32_16x16x16bf16_1k(a, b, c, 0, 0, 0);
#else
  f32x4 d = c;
  asm("v_mfma_f32_16x16x16_bf16 %0, %1, %2, %0" : "+v"(d) : "v"(a), "v"(b));
  return d;
#endif
}

// Coalesced prep. Blocks 0..31: W1 (e = blk>>2, n0 = (blk&3)*64).
// Blocks 32..39: W2, one expert each (R7's single W2 block with 64 serial
// gather iters was the prep straggler).
__global__ __launch_bounds__(256) void prep(const float* __restrict__ W1,
                                            const float* __restrict__ W2,
                                            unsigned short* __restrict__ W1T,
                                            unsigned short* __restrict__ W2T) {
  const int t = threadIdx.x;
  if (blockIdx.x < 32) {
    // W1 [8][90][256] f32 -> W1T[(e*256+n)*96 + kp] bf16, kp>=90 zero-padded
    const int e = blockIdx.x >> 2;
    const int n0 = (blockIdx.x & 3) * 64;
    __shared__ unsigned int ld[64][49];  // stride 49 = 17 mod 32 -> conflict-free
    const int nl = t & 63;
    const int kq = t >> 6;
#pragma unroll
    for (int j = 0; j < 12; ++j) {
      const int kp2 = kq + 4 * j;  // 0..47
      const int k0 = 2 * kp2, k1 = k0 + 1;
      unsigned int lo = 0, hi = 0;
      if (k0 < DIN) lo = f2bf(W1[((size_t)e * DIN + k0) * NH + n0 + nl]);  // coalesced
      if (k1 < DIN) hi = f2bf(W1[((size_t)e * DIN + k1) * NH + n0 + nl]);
      ld[nl][kp2] = lo | (hi << 16);
    }
    __syncthreads();
    unsigned int* dst = (unsigned int*)(W1T + (size_t)(e * NH + n0) * 96);
#pragma unroll
    for (int j = 0; j < 12; ++j) {
      const int u = t + 256 * j;
      dst[u] = ld[u / 48][u % 48];  // 3072 contiguous dwords, fully coalesced
    }
  } else {
    // W2 [8][256][4] f32 -> W2T2[e][hb][o][k16] bf16 (hb=k>>4, k16=k&15; o>=4 zero)
    const int e = blockIdx.x - 32;
    unsigned int* dst = (unsigned int*)W2T + (size_t)e * 2048;
    const float* src = W2 + (size_t)e * 1024;
#pragma unroll
    for (int j = 0; j < 8; ++j) {
      const int u = t + 256 * j;  // 0..2047, stores coalesced
      const int m = u & 7;        // k16 pair
      const int o = (u >> 3) & 15;
      const int hb = (u >> 7) & 15;
      unsigned int lo = 0, hi = 0;
      if (o < 4) {
        lo = f2bf(src[(hb * 16 + 2 * m) * 4 + o]);
        hi = f2bf(src[(hb * 16 + 2 * m + 1) * 4 + o]);
      }
      dst[u] = lo | (hi << 16);
    }
  }
}

// R8: occupancy is the binding constraint. R7 counters: MfmaUtil 27%, pure
// VALU ~12% (VALUBusy includes MFMA on gfx94x-fallback formulas) -> ~60% of
// wall is all-wave stall at 3 blocks/CU (Occupancy 29%). Go (256,4) = 128-reg
// cap, paid for by trimming prefetch state: only mf0's W1 frags stay
// double-buffered; mf1 frags + w2f load at iteration top (first consumed after
// ~12 MFMAs of matrix-pipe time -> L2 latency covered). Net -16 live regs vs
// R7. Falsifier: WRITE_SIZE >> 2048 KB means the cap spilled.
__global__ __launch_bounds__(256, 4) void meganerf_main(
    const float* __restrict__ x, const float* __restrict__ cent,
    const float* __restrict__ b1, const float* __restrict__ b2,
    const unsigned short* __restrict__ W1T, const unsigned short* __restrict__ W2T,
    float* __restrict__ out) {
  __shared__ float sOut[4][64][4];         // 4096 B cross-wave reduction staging
  __shared__ float sW[NE][64];             // 2048 B
  __shared__ float sB2[64][4];             // 1024 B
  __shared__ float sB1[NE * NH];           // 8192 B  -> total 15360 B

  const int t    = threadIdx.x;
  const int lane = t & 63;
  const int wid  = t >> 6;
  const int l15  = lane & 15;
  const int l4   = lane >> 4;
  const int row0 = blockIdx.x * 64;

  // ---- stage b1 -> LDS (coalesced) ----
#pragma unroll
  for (int j = 0; j < 2; ++j)
    *(f32x4*)&sB1[t * 4 + j * 1024] = *(const f32x4a*)&b1[t * 4 + j * 1024];

  // ---- feat fragments (MFMA B operand B[k][n=row]), regs for all experts ----
  bf16x8 bfr[4][3];
#pragma unroll
  for (int nf = 0; nf < 4; ++nf) {
    const float* gr = x + (size_t)(row0 + 16 * nf + l15) * 93 + 3;
    f32x4 v0, v1;
    v0 = *(const f32x4a*)(gr + 8 * l4);
    v1 = *(const f32x4a*)(gr + 8 * l4 + 4);
    bfr[nf][0] = cvt8(v0, v1);
    v0 = *(const f32x4a*)(gr + 32 + 8 * l4);
    v1 = *(const f32x4a*)(gr + 36 + 8 * l4);
    bfr[nf][1] = cvt8(v0, v1);
    if (l4 < 3) {
      v0 = *(const f32x4a*)(gr + 64 + 8 * l4);
      v1 = *(const f32x4a*)(gr + 68 + 8 * l4);
    } else {
      f32x2 tl = *(const f32x2a*)(gr + 88);
      v0[0] = tl[0]; v0[1] = tl[1]; v0[2] = 0.f; v0[3] = 0.f;
      v1[0] = 0.f; v1[1] = 0.f; v1[2] = 0.f; v1[3] = 0.f;
    }
    bfr[nf][2] = cvt8(v0, v1);
  }

  // ---- per-point expert weights ----
  if (t < 64) {
    const float* gx = x + (size_t)(row0 + t) * 93;
    float px = gx[0], py = gx[1], pz = gx[2];
    float dist[NE], inv[NE];
    float mind = 3.4e38f;
#pragma unroll
    for (int e = 0; e < NE; ++e) {
      float dx = px - cent[e * 3 + 0];
      float dy = py - cent[e * 3 + 1];
      float dz = pz - cent[e * 3 + 2];
      float d2 = dx * dx + dy * dy + dz * dz;
      float d = sqrtf(fmaxf(d2, 0.f));
      dist[e] = d;
      inv[e] = 1.f / (d + 1e-8f);
      mind = fminf(mind, d);
    }
    float s = 0.f;
#pragma unroll
    for (int e = 0; e < NE; ++e) {
      if (dist[e] > 2.0f * mind) inv[e] = 0.f;
      s += inv[e];
    }
    float rs = 1.f / s;
    float bb[4] = {0.f, 0.f, 0.f, 0.f};
#pragma unroll
    for (int e = 0; e < NE; ++e) {
      float w = inv[e] * rs;
      sW[e][t] = w;
#pragma unroll
      for (int o = 0; o < 4; ++o) bb[o] += w * b2[e * 4 + o];
    }
#pragma unroll
    for (int o = 0; o < 4; ++o) sB2[t][o] = bb[o];
  }
  __syncthreads();   // covers sB1, sW, sB2

  // ---- pipelined (expert, chunk) loop ----
  bf16x8 w1m0[2][3];  // mf0 W1 frags, double-buffered (consumed at iter top)
  bf16x8 w1m1[3];     // mf1 W1 frags, single-buffered (consumed after 12 MFMAs)
  bf16x4 w2f[2];      // W2 B-frags [mf], single-buffered (consumed at epilogues)
  float wv[4];

  auto loadW1mf0 = [&](int idx, int buf) {
    const int e = idx >> 1, c = idx & 1;
    const unsigned short* p =
        W1T + (size_t)(e * NH + 128 * c + 32 * wid + l15) * 96 + 8 * l4;
#pragma unroll
    for (int ks = 0; ks < 3; ++ks)
      w1m0[buf][ks] = *(const bf16x8*)(p + 32 * ks);
  };
  auto loadW1mf1 = [&](int idx) {
    const int e = idx >> 1, c = idx & 1;
    const unsigned short* p =
        W1T + (size_t)(e * NH + 128 * c + 32 * wid + 16 + l15) * 96 + 8 * l4;
#pragma unroll
    for (int ks = 0; ks < 3; ++ks)
      w1m1[ks] = *(const bf16x8*)(p + 32 * ks);
  };
  auto loadW2 = [&](int idx) {
    const int e = idx >> 1, c = idx & 1;
    const int hb0 = 8 * c + 2 * wid;  // hidden16-block; mf=1 is hb0+1
    const unsigned short* p = W2T + ((size_t)(e * 16 + hb0) * 256) + l15 * 16 + l4 * 4;
    w2f[0] = *(const bf16x4*)(p);
    w2f[1] = *(const bf16x4*)(p + 256);
  };

  loadW1mf0(0, 0);

  f32x4 facc[4] = {{0.f, 0.f, 0.f, 0.f}, {0.f, 0.f, 0.f, 0.f},
                   {0.f, 0.f, 0.f, 0.f}, {0.f, 0.f, 0.f, 0.f}};

#pragma unroll 2
  for (int i = 0; i < 16; ++i) {
    const int e = i >> 1, c = i & 1, cur = i & 1, nxt = cur ^ 1;
    const int colbase = 128 * c + 32 * wid;

    // current-iter LDS operands (issue early; ~120cy latency)
    f32x4 b1v0 = *(const f32x4*)&sB1[e * NH + colbase + 4 * l4];
    f32x4 b1v1 = *(const f32x4*)&sB1[e * NH + colbase + 16 + 4 * l4];
    if (c == 0) {
#pragma unroll
      for (int nf = 0; nf < 4; ++nf) wv[nf] = sW[e][16 * nf + l15];
    }

    // VMEM, FIFO order of consumption: this iter's mf1 frags (needed after 12
    // MFMAs), this iter's w2 frags (needed at mf0 epilogue), next iter's mf0
    // frags (needed next iter top).
    loadW1mf1(i);
    loadW2(i);
    loadW1mf0((i + 1) & 15, nxt);

    // ---- layer 1 mf0 (w1m0[cur] loaded last iter -> no fresh-load wait) ----
    f32x4 acc[4];
#pragma unroll
    for (int nf = 0; nf < 4; ++nf)
      acc[nf] = __builtin_amdgcn_mfma_f32_16x16x32_bf16(
          w1m0[cur][0], bfr[nf][0], b1v0, 0, 0, 0);
#pragma unroll
    for (int ks = 1; ks < 3; ++ks)
#pragma unroll
      for (int nf = 0; nf < 4; ++nf)
        acc[nf] = __builtin_amdgcn_mfma_f32_16x16x32_bf16(
            w1m0[cur][ks], bfr[nf][ks], acc[nf], 0, 0, 0);

    // mf0 epilogue: relu*w, pack -> layer-2 A-frag -> mfma16
#pragma unroll
    for (int nf = 0; nf < 4; ++nf) {
      const float w = wv[nf];
      f32x4 a = acc[nf];
      f32x2 p0, p1;
      p0[0] = a[0]; p0[1] = a[1];
      p1[0] = a[2]; p1[1] = a[3];
      const f32x2 z = {0.f, 0.f};
      p0 = __builtin_elementwise_max(p0, z) * w;
      p1 = __builtin_elementwise_max(p1, z) * w;
      u32x2 pk;
      pk[0] = pkbf(p0[0], p0[1]);
      pk[1] = pkbf(p1[0], p1[1]);
      facc[nf] = mfma16(__builtin_bit_cast(bf16x4, pk), w2f[0], facc[nf]);
    }

    // ---- layer 1 mf1 (w1m1 loaded this iter; 12 MFMAs of cover) ----
#pragma unroll
    for (int nf = 0; nf < 4; ++nf)
      acc[nf] = __builtin_amdgcn_mfma_f32_16x16x32_bf16(
          w1m1[0], bfr[nf][0], b1v1, 0, 0, 0);
#pragma unroll
    for (int ks = 1; ks < 3; ++ks)
#pragma unroll
      for (int nf = 0; nf < 4; ++nf)
        acc[nf] = __builtin_amdgcn_mfma_f32_16x16x32_bf16(
            w1m1[ks], bfr[nf][ks], acc[nf], 0, 0, 0);

    // mf1 epilogue
#pragma unroll
    for (int nf = 0; nf < 4; ++nf) {
      const float w = wv[nf];
      f32x4 a = acc[nf];
      f32x2 p0, p1;
      p0[0] = a[0]; p0[1] = a[1];
      p1[0] = a[2]; p1[1] = a[3];
      const f32x2 z = {0.f, 0.f};
      p0 = __builtin_elementwise_max(p0, z) * w;
      p1 = __builtin_elementwise_max(p1, z) * w;
      u32x2 pk;
      pk[0] = pkbf(p0[0], p0[1]);
      pk[1] = pkbf(p1[0], p1[1]);
      facc[nf] = mfma16(__builtin_bit_cast(bf16x4, pk), w2f[1], facc[nf]);
    }
  }

  // ---- cross-wave reduction ----
  // facc layout: D[row=point-in-16 = l4*4+r][col=o = l15] per nf block.
  if (l15 < 4) {
#pragma unroll
    for (int nf = 0; nf < 4; ++nf)
#pragma unroll
      for (int r = 0; r < 4; ++r)
        sOut[wid][16 * nf + 4 * l4 + r][l15] = facc[nf][r];
  }
  __syncthreads();
  {
    const int row = t >> 2, o = t & 3;
    float v = sB2[row][o] + sOut[0][row][o] + sOut[1][row][o] +
              sOut[2][row][o] + sOut[3][row][o];
    out[row0 * 4 + t] = v;
  }
}

extern "C" void kernel_launch(void* const* d_in, const int* in_sizes, int n_in,
                              void* d_out, int out_size, void* d_ws, size_t ws_size,
                              hipStream_t stream) {
  const float* x    = (const float*)d_in[0];
  const float* cent = (const float*)d_in[1];
  const float* W1   = (const float*)d_in[2];
  const float* b1   = (const float*)d_in[3];
  const float* W2   = (const float*)d_in[4];
  const float* b2   = (const float*)d_in[5];
  float* out = (float*)d_out;

  unsigned short* W1T = (unsigned short*)d_ws;   // 393216 B
  unsigned short* W2T = W1T + NE * NH * 96;      // 65536 B (W2T2 layout)

  prep<<<40, 256, 0, stream>>>(W1, W2, W1T, W2T);
  meganerf_main<<<NPTS / 64, 256, 0, stream>>>(x, cent, b1, b2, W1T, W2T, out);
}

// Round 4
// 163.595 us; speedup vs baseline: 1.5835x; 1.5835x over previous
//
#include <hip/hip_runtime.h>

#define NPTS 131072
#define NE 8
#define DIN 90
#define NH 256

typedef __attribute__((ext_vector_type(8))) short bf16x8;
typedef __attribute__((ext_vector_type(4))) float f32x4;
typedef __attribute__((ext_vector_type(2))) float f32x2;
typedef __attribute__((ext_vector_type(4))) unsigned int u32x4;
typedef __attribute__((ext_vector_type(2))) unsigned int u32x2;
typedef __attribute__((ext_vector_type(4), aligned(4))) float f32x4a;
typedef __attribute__((ext_vector_type(2), aligned(4))) float f32x2a;

// exact RNE scalar (prep only)
__device__ __forceinline__ unsigned short f2bf(float f) {
  unsigned int u = __float_as_uint(f);
  u += 0x7fffu + ((u >> 16) & 1u);
  return (unsigned short)(u >> 16);
}

#if defined(__has_builtin) && __has_builtin(__builtin_amdgcn_cvt_pk_bf16_f32)
typedef __attribute__((ext_vector_type(2))) __bf16 bf16x2;
__device__ __forceinline__ unsigned int pkbf(float f0, float f1) {
  bf16x2 r = __builtin_amdgcn_cvt_pk_bf16_f32(f0, f1);
  return __builtin_bit_cast(unsigned int, r);
}
#else
__device__ __forceinline__ unsigned int pkbf(float f0, float f1) {
  unsigned int u0 = __float_as_uint(f0) + 0x7fffu;
  unsigned int u1 = __float_as_uint(f1) + 0x7fffu;
  return __builtin_amdgcn_perm(u1, u0, 0x07060302u);
}
#endif

__device__ __forceinline__ bf16x8 cvt8(f32x4 a, f32x4 b) {
  u32x4 r;
  r[0] = pkbf(a[0], a[1]);
  r[1] = pkbf(a[2], a[3]);
  r[2] = pkbf(b[0], b[1]);
  r[3] = pkbf(b[2], b[3]);
  return __builtin_bit_cast(bf16x8, r);
}

// Coalesced prep (R3 version — validated). Blocks 0..31: W1 (e = blk>>2,
// n0 = (blk&3)*64). Blocks 32..39: W2, one expert each.
__global__ __launch_bounds__(256) void prep(const float* __restrict__ W1,
                                            const float* __restrict__ W2,
                                            unsigned short* __restrict__ W1T,
                                            unsigned short* __restrict__ W2T) {
  const int t = threadIdx.x;
  if (blockIdx.x < 32) {
    // W1 [8][90][256] f32 -> W1T[(e*256+n)*96 + kp] bf16, kp>=90 zero-padded
    const int e = blockIdx.x >> 2;
    const int n0 = (blockIdx.x & 3) * 64;
    __shared__ unsigned int ld[64][49];  // stride 49 = 17 mod 32 -> conflict-free
    const int nl = t & 63;
    const int kq = t >> 6;
#pragma unroll
    for (int j = 0; j < 12; ++j) {
      const int kp2 = kq + 4 * j;  // 0..47
      const int k0 = 2 * kp2, k1 = k0 + 1;
      unsigned int lo = 0, hi = 0;
      if (k0 < DIN) lo = f2bf(W1[((size_t)e * DIN + k0) * NH + n0 + nl]);  // coalesced
      if (k1 < DIN) hi = f2bf(W1[((size_t)e * DIN + k1) * NH + n0 + nl]);
      ld[nl][kp2] = lo | (hi << 16);
    }
    __syncthreads();
    unsigned int* dst = (unsigned int*)(W1T + (size_t)(e * NH + n0) * 96);
#pragma unroll
    for (int j = 0; j < 12; ++j) {
      const int u = t + 256 * j;
      dst[u] = ld[u / 48][u % 48];  // 3072 contiguous dwords, fully coalesced
    }
  } else {
    // W2 [8][256][4] f32 -> W2T[(e*16+o)*NH + k] bf16, o>=4 zero-padded
    const int e = blockIdx.x - 32;
    unsigned int* dst = (unsigned int*)W2T + (size_t)e * 2048;  // 16*256 bf16 = 2048 dw
    const float* src = W2 + (size_t)e * 1024;
#pragma unroll
    for (int j = 0; j < 8; ++j) {
      const int u = t + 256 * j;  // 0..2047 dwords, stores coalesced
      const int o = u >> 7;       // 0..15
      const int kp = u & 127;     // k pair
      unsigned int v = 0;
      if (o < 4) {
        unsigned int lo = f2bf(src[(2 * kp) * 4 + o]);
        unsigned int hi = f2bf(src[(2 * kp + 1) * 4 + o]);
        v = lo | (hi << 16);
      }
      dst[u] = v;
    }
  }
}

// R9: exact R0 structure (fastest measured: 97-101us main) + s_setprio around
// MFMA clusters. Regime check for T5: this loop has NO __syncthreads — the 3
// waves/SIMD drift independently (attn-like regime where setprio gave +4-7%;
// the GEMM-null case was barrier-lockstep). launch_bounds (256,3): cap 170
// regs -> no spills. True unified footprint ~80 VGPR + 64 AGPR = 144 -> 3
// waves/SIMD; R8 proved (256,4) spills catastrophically (live ~160 > 128).
__global__ __launch_bounds__(256, 3) void meganerf_main(
    const float* __restrict__ x, const float* __restrict__ cent,
    const float* __restrict__ b1, const float* __restrict__ b2,
    const unsigned short* __restrict__ W1T, const unsigned short* __restrict__ W2T,
    float* __restrict__ out) {
  __shared__ unsigned short sH[4 * 2048];  // 16384 B wave-private h (A-frag order)
  __shared__ float sW[NE][64];             // 2048 B
  __shared__ float sB2[64][4];             // 1024 B
  __shared__ float sB1[NE * NH];           // 8192 B  -> total 27648 B

  const int t    = threadIdx.x;
  const int lane = t & 63;
  const int wid  = t >> 6;
  const int l15  = lane & 15;
  const int l4   = lane >> 4;
  const int row0 = blockIdx.x * 64;
  const int gbase = wid * 2048;

  // ---- stage b1 -> LDS (coalesced) ----
#pragma unroll
  for (int j = 0; j < 2; ++j)
    *(f32x4*)&sB1[t * 4 + j * 1024] = *(const f32x4a*)&b1[t * 4 + j * 1024];

  // ---- feat fragments (MFMA B operand B[k][n=row]), regs for all experts ----
  bf16x8 bfr[4][3];
#pragma unroll
  for (int nf = 0; nf < 4; ++nf) {
    const float* gr = x + (size_t)(row0 + 16 * nf + l15) * 93 + 3;
    f32x4 v0, v1;
    v0 = *(const f32x4a*)(gr + 8 * l4);
    v1 = *(const f32x4a*)(gr + 8 * l4 + 4);
    bfr[nf][0] = cvt8(v0, v1);
    v0 = *(const f32x4a*)(gr + 32 + 8 * l4);
    v1 = *(const f32x4a*)(gr + 36 + 8 * l4);
    bfr[nf][1] = cvt8(v0, v1);
    if (l4 < 3) {
      v0 = *(const f32x4a*)(gr + 64 + 8 * l4);
      v1 = *(const f32x4a*)(gr + 68 + 8 * l4);
    } else {
      f32x2 tl = *(const f32x2a*)(gr + 88);
      v0[0] = tl[0]; v0[1] = tl[1]; v0[2] = 0.f; v0[3] = 0.f;
      v1[0] = 0.f; v1[1] = 0.f; v1[2] = 0.f; v1[3] = 0.f;
    }
    bfr[nf][2] = cvt8(v0, v1);
  }

  // ---- per-point expert weights ----
  if (t < 64) {
    const float* gx = x + (size_t)(row0 + t) * 93;
    float px = gx[0], py = gx[1], pz = gx[2];
    float dist[NE], inv[NE];
    float mind = 3.4e38f;
#pragma unroll
    for (int e = 0; e < NE; ++e) {
      float dx = px - cent[e * 3 + 0];
      float dy = py - cent[e * 3 + 1];
      float dz = pz - cent[e * 3 + 2];
      float d2 = dx * dx + dy * dy + dz * dz;
      float d = sqrtf(fmaxf(d2, 0.f));
      dist[e] = d;
      inv[e] = 1.f / (d + 1e-8f);
      mind = fminf(mind, d);
    }
    float s = 0.f;
#pragma unroll
    for (int e = 0; e < NE; ++e) {
      if (dist[e] > 2.0f * mind) inv[e] = 0.f;
      s += inv[e];
    }
    float rs = 1.f / s;
    float bb[4] = {0.f, 0.f, 0.f, 0.f};
#pragma unroll
    for (int e = 0; e < NE; ++e) {
      float w = inv[e] * rs;
      sW[e][t] = w;
#pragma unroll
      for (int o = 0; o < 4; ++o) bb[o] += w * b2[e * 4 + o];
    }
#pragma unroll
    for (int o = 0; o < 4; ++o) sB2[t][o] = bb[o];
  }
  __syncthreads();   // covers sB1, sW, sB2

  // ---- pipelined (expert, chunk) loop ----
  bf16x8 w1buf[2][6];   // W1T frags, prefetched one chunk ahead
  bf16x8 bwbuf[2];      // W2T frag, prefetched ahead, issued BEFORE w1 group
  float wv[4];

  auto loadW1 = [&](int idx, int buf) {
    const int e = idx >> 1, c = idx & 1;
    const unsigned short* p =
        W1T + (size_t)(e * NH + 128 * c + 32 * wid + l15) * 96 + 8 * l4;
#pragma unroll
    for (int mf = 0; mf < 2; ++mf)
#pragma unroll
      for (int ks = 0; ks < 3; ++ks)
        w1buf[buf][mf * 3 + ks] = *(const bf16x8*)(p + mf * (16 * 96) + 32 * ks);
  };
  auto loadBW = [&](int idx, int buf) {
    const int e = idx >> 1, c = idx & 1;
    bwbuf[buf] = *(const bf16x8*)(W2T + (size_t)(e * 16 + l15) * NH +
                                  128 * c + 32 * wid + 8 * l4);
  };

  loadBW(0, 0);
  loadW1(0, 0);

  f32x4 facc[4] = {{0.f, 0.f, 0.f, 0.f}, {0.f, 0.f, 0.f, 0.f},
                   {0.f, 0.f, 0.f, 0.f}, {0.f, 0.f, 0.f, 0.f}};

#pragma unroll 2
  for (int i = 0; i < 16; ++i) {
    const int e = i >> 1, c = i & 1, cur = i & 1, nxt = cur ^ 1;
    const int colbase = 128 * c + 32 * wid;

    // current-iter LDS operands (issue early; ~120cy latency)
    f32x4 b1v0 = *(const f32x4*)&sB1[e * NH + colbase + 4 * l4];
    f32x4 b1v1 = *(const f32x4*)&sB1[e * NH + colbase + 16 + 4 * l4];
    if (c == 0) {
#pragma unroll
      for (int nf = 0; nf < 4; ++nf) wv[nf] = sW[e][16 * nf + l15];
    }

    // next-iter VMEM prefetch: bw FIRST (vmcnt FIFO), then the 6 W1T frags
    const int ip = (i + 1) & 15;
    loadBW(ip, nxt);
    loadW1(ip, nxt);

    // ---- layer 1, mf-sequential (16 AGPR live) ----
#pragma unroll
    for (int mf = 0; mf < 2; ++mf) {
      const f32x4 b1v = (mf == 0) ? b1v0 : b1v1;
      f32x4 acc[4];
      __builtin_amdgcn_s_setprio(1);   // own the matrix pipe for this cluster
#pragma unroll
      for (int nf = 0; nf < 4; ++nf)
        acc[nf] = __builtin_amdgcn_mfma_f32_16x16x32_bf16(
            w1buf[cur][mf * 3 + 0], bfr[nf][0], b1v, 0, 0, 0);
#pragma unroll
      for (int ks = 1; ks < 3; ++ks)
#pragma unroll
        for (int nf = 0; nf < 4; ++nf)
          acc[nf] = __builtin_amdgcn_mfma_f32_16x16x32_bf16(
              w1buf[cur][mf * 3 + ks], bfr[nf][ks], acc[nf], 0, 0, 0);
      __builtin_amdgcn_s_setprio(0);

      // epilogue: relu*w, pack, wave-private A-frag-order store
#pragma unroll
      for (int nf = 0; nf < 4; ++nf) {
        const float w = wv[nf];
        f32x4 a = acc[nf];
        f32x2 p0, p1;
        p0[0] = a[0]; p0[1] = a[1];
        p1[0] = a[2]; p1[1] = a[3];
        const f32x2 z = {0.f, 0.f};
        p0 = __builtin_elementwise_max(p0, z) * w;
        p1 = __builtin_elementwise_max(p1, z) * w;
        u32x2 pk;
        pk[0] = pkbf(p0[0], p0[1]);
        pk[1] = pkbf(p1[0], p1[1]);
        *(u32x2*)&sH[gbase + (nf * 64 + (l15 + 16 * (2 * mf + (l4 >> 1)))) * 8 +
                     4 * (l4 & 1)] = pk;
      }
    }

    // ---- layer 2 (wave-private; bwbuf[cur] loaded LAST iter -> no vm drain) ----
    __builtin_amdgcn_s_setprio(1);
#pragma unroll
    for (int rf = 0; rf < 4; ++rf) {
      bf16x8 ah = *(const bf16x8*)&sH[gbase + (rf * 64 + lane) * 8];
      facc[rf] = __builtin_amdgcn_mfma_f32_16x16x32_bf16(ah, bwbuf[cur], facc[rf], 0, 0, 0);
    }
    __builtin_amdgcn_s_setprio(0);
  }

  // ---- cross-wave reduction (sOutP aliased onto sH: 4*64*4 f32 = 4 KB) ----
  __syncthreads();
  float* sOutP = (float*)sH;
  if (l15 < 4) {
#pragma unroll
    for (int rf = 0; rf < 4; ++rf)
#pragma unroll
      for (int r = 0; r < 4; ++r)
        sOutP[(wid * 64 + 16 * rf + 4 * l4 + r) * 4 + l15] = facc[rf][r];
  }
  __syncthreads();
  {
    const int row = t >> 2, o = t & 3;
    float v = sB2[row][o] + sOutP[(0 * 64 + row) * 4 + o] + sOutP[(1 * 64 + row) * 4 + o] +
              sOutP[(2 * 64 + row) * 4 + o] + sOutP[(3 * 64 + row) * 4 + o];
    out[row0 * 4 + t] = v;
  }
}

extern "C" void kernel_launch(void* const* d_in, const int* in_sizes, int n_in,
                              void* d_out, int out_size, void* d_ws, size_t ws_size,
                              hipStream_t stream) {
  const float* x    = (const float*)d_in[0];
  const float* cent = (const float*)d_in[1];
  const float* W1   = (const float*)d_in[2];
  const float* b1   = (const float*)d_in[3];
  const float* W2   = (const float*)d_in[4];
  const float* b2   = (const float*)d_in[5];
  float* out = (float*)d_out;

  unsigned short* W1T = (unsigned short*)d_ws;   // 393216 B
  unsigned short* W2T = W1T + NE * NH * 96;      // 65536 B

  prep<<<40, 256, 0, stream>>>(W1, W2, W1T, W2T);
  meganerf_main<<<NPTS / 64, 256, 0, stream>>>(x, cent, b1, b2, W1T, W2T, out);
}